// Round 1
// baseline (163.497 us; speedup 1.0000x reference)
//
#include <hip/hip_runtime.h>

// ConvexWidthUpsampler: fused conv3x3(1->32) + PReLU + conv1x1(32->27)
// + softmax(9, per v) + convex combination of the 3x3 neighborhood.
// B=16, C=1, H=512, W=512, up_h=1, up_w=3. Output [16,1,512,1536] f32.

#define BB 16
#define HH 512
#define WW 512
#define HID 32
#define NM 27   // 9 * up_h(1) * up_w(3)

__global__ __launch_bounds__(256) void convex_upsample_fused(
    const float* __restrict__ x,     // [16,1,512,512]
    const float* __restrict__ w1,    // [32,1,3,3]
    const float* __restrict__ b1,    // [32]
    const float* __restrict__ alpha, // [32]
    const float* __restrict__ w2,    // [27,32,1,1]
    const float* __restrict__ b2,    // [27]
    float* __restrict__ out)         // [16,1,512,1536]
{
    const int p  = blockIdx.x * 256 + threadIdx.x;   // 0 .. 16*512*512-1
    const int wcol = p & (WW - 1);
    const int t  = p >> 9;           // b*H + h
    const int hrow = t & (HH - 1);
    const int bidx = t >> 9;

    const float* xb = x + (size_t)bidx * (HH * WW);

    // 3x3 neighborhood with zero padding (shared by conv3x3 and unfold)
    float xv[9];
#pragma unroll
    for (int ki = 0; ki < 3; ++ki) {
        const int hy = hrow + ki - 1;
        const bool hok = (unsigned)hy < (unsigned)HH;
#pragma unroll
        for (int kj = 0; kj < 3; ++kj) {
            const int wx = wcol + kj - 1;
            const bool ok = hok && ((unsigned)wx < (unsigned)WW);
            xv[ki * 3 + kj] = ok ? xb[hy * WW + wx] : 0.0f;
        }
    }

    // conv3x3 -> PReLU  (weights are wave-uniform: constant offsets -> s_load)
    float hbuf[HID];
#pragma unroll
    for (int c = 0; c < HID; ++c) {
        float acc = b1[c];
#pragma unroll
        for (int k = 0; k < 9; ++k) acc = fmaf(w1[c * 9 + k], xv[k], acc);
        hbuf[c] = acc > 0.0f ? acc : alpha[c] * acc;
    }

    // conv1x1: 27 logits
    float m[NM];
#pragma unroll
    for (int j = 0; j < NM; ++j) {
        float acc = b2[j];
#pragma unroll
        for (int c = 0; c < HID; ++c) acc = fmaf(w2[j * HID + c], hbuf[c], acc);
        m[j] = acc;
    }

    // per-v softmax over k=0..8, fused with the convex combination
    // m layout: j = k*3 + v  (up_h=1)
    float o[3];
#pragma unroll
    for (int v = 0; v < 3; ++v) {
        float mx = m[v];
#pragma unroll
        for (int k = 1; k < 9; ++k) mx = fmaxf(mx, m[k * 3 + v]);
        float s = 0.0f, acc = 0.0f;
#pragma unroll
        for (int k = 0; k < 9; ++k) {
            const float e = __expf(m[k * 3 + v] - mx);
            s += e;
            acc = fmaf(xv[k], e, acc);
        }
        o[v] = acc * __builtin_amdgcn_rcpf(s);
    }

    const size_t ob = ((size_t)(bidx * HH + hrow) * (WW * 3)) + (size_t)wcol * 3;
    out[ob + 0] = o[0];
    out[ob + 1] = o[1];
    out[ob + 2] = o[2];
}

extern "C" void kernel_launch(void* const* d_in, const int* in_sizes, int n_in,
                              void* d_out, int out_size, void* d_ws, size_t ws_size,
                              hipStream_t stream) {
    // setup_inputs order: x, target_h, target_w, w1, b1, alpha, w2, b2
    const float* x     = (const float*)d_in[0];
    const float* w1    = (const float*)d_in[3];
    const float* b1    = (const float*)d_in[4];
    const float* alpha = (const float*)d_in[5];
    const float* w2    = (const float*)d_in[6];
    const float* b2    = (const float*)d_in[7];
    float* out = (float*)d_out;

    const int total  = BB * HH * WW;          // 4,194,304
    const int blocks = total / 256;           // 16,384
    hipLaunchKernelGGL(convex_upsample_fused, dim3(blocks), dim3(256), 0, stream,
                       x, w1, b1, alpha, w2, b2, out);
}